// Round 9
// baseline (454.377 us; speedup 1.0000x reference)
//
#include <hip/hip_runtime.h>

// BiLSTM: B=256, T=512, N=128, H=128. fp32 in/out, bf16 MFMA internally.
//
// 128 blocks = 2 dirs x 64 batch-blocks of 4 rows. h@U uses padded M=16 tile
// (real batch rows at tile rows {0,4,8,12}; padding rows permanent zero).
// 8 waves; wave = column-slice tc (16 cols x all 4 gates).
// Dense 4-step-batched x@W (round 6): one dense M=16 tile per 4 steps,
// row = 4*br + ts; accX[g][r] = zx for (row quad, step 4G+r, col tc*16+m).
//
// Round-9 change vs round-8 (319us kernel): per-gate MFMA/VALU interleave.
//   Round-8 PMC: active-scaled MfmaUtil 43% + VALUBusy 41% = 84% of step --
//   the two waves per SIMD run [all 20 MFMA][all VALU] in lockstep, so the
//   pipes serialize (step = sum, not max). Permanent setprio alone was null:
//   identical clustered streams give arbitration nothing to de-phase.
//   Now each substep is a per-gate pipeline (gate chain -> that gate's
//   activation while the next chain occupies the matrix pipe), pinned with
//   sched_group_barrier: {DS_READ 4, MFMA 4, MFMA 4, VALU 4, MFMA 4,
//   VALU 4, MFMA 4, VALU 7, MFMA 4, VALU 20, DS_WRITE 1}. A wave in a VALU
//   gap yields matrix slots to its SIMD partner; setprio amplifies skew.
//   Per-gate chain order unchanged -> bit-identical output.
//
// ws layout:
//   [0, 512KB): combined WU bf16 B-fragments
//               [dir(2)][gate(4)][kc(8)][tile(8)][lane(64)][8]
//               kc<4 -> W rows kc*32.., kc>=4 -> U rows (kc-4)*32..

typedef short s16x8 __attribute__((ext_vector_type(8)));
typedef float f32x4 __attribute__((ext_vector_type(4)));

#define NT 512
#define NG 128          // groups of 4 steps

// Barrier with LDS-only drain: out-stores and x prefetches stay in flight.
#define LDS_BARRIER() asm volatile("s_waitcnt lgkmcnt(0)\n\ts_barrier" ::: "memory")

#define SGB __builtin_amdgcn_sched_group_barrier
// masks: VALU=0x2 MFMA=0x8 DS_READ=0x100 DS_WRITE=0x200

__device__ __forceinline__ unsigned short f2bf(float f) {
  unsigned int u = __float_as_uint(f);
  u += 0x7fffu + ((u >> 16) & 1u);   // RNE
  return (unsigned short)(u >> 16);
}
__device__ __forceinline__ unsigned int packbf2(float a, float b) {
  return (unsigned int)f2bf(a) | ((unsigned int)f2bf(b) << 16);
}
__device__ __forceinline__ float sigm(float x) {
  return __builtin_amdgcn_rcpf(1.f + __expf(-x));
}
__device__ __forceinline__ float tanh_(float x) {
  float xc = fminf(fmaxf(x, -12.f), 12.f);
  return 1.f - 2.f * __builtin_amdgcn_rcpf(1.f + __expf(2.f * xc));
}

// ---------------------------------------------------------------- kernel 0
// Repack [W;U] (fp32 [128][512] each) into bf16 B-fragment order, K=256.
// B-frag (16x16x32): lane holds B[k = (lane>>4)*8 + j][n = lane&15].
__global__ void prep_frags(const float* __restrict__ Wf, const float* __restrict__ Uf,
                           const float* __restrict__ Wb, const float* __restrict__ Ub,
                           unsigned short* __restrict__ frag) {
  int idx = blockIdx.x * 256 + threadIdx.x;          // 0 .. 2^18-1
  int j    = idx & 7;
  int lane = (idx >> 3) & 63;
  int tile = (idx >> 9) & 7;
  int kc   = (idx >> 12) & 7;
  int gate = (idx >> 15) & 3;
  int dir  = (idx >> 17) & 1;
  const float* M = (kc < 4) ? (dir ? Wb : Wf) : (dir ? Ub : Uf);
  int k   = (kc & 3) * 32 + (lane >> 4) * 8 + j;
  int col = gate * 128 + tile * 16 + (lane & 15);
  frag[idx] = f2bf(M[k * 512 + col]);
}

// ---------------------------------------------------------------- kernel 1
__global__ __launch_bounds__(512, 2) void bilstm_rec(
    const unsigned short* __restrict__ frag, const float* __restrict__ x,
    const float* __restrict__ bfw, const float* __restrict__ bbw,
    float* __restrict__ out) {
  __shared__ unsigned short hbuf[2][16][136];   // h; rows {0,4,8,12} live
  __shared__ unsigned short xbuf[2][16][136];   // x; row 4*br+ts, per-group

  int bid = blockIdx.x;
  int bblk = bid & 63, dir = bid >> 6;
  int tid = threadIdx.x;
  int tc = tid >> 6, lane = tid & 63, quad = lane >> 4, m = lane & 15;
  bool mrow = ((m & 3) == 0);   // lane holds a real h-row

  // Anti-phase amplifier for the two waves sharing a SIMD (w, w+4).
  if (tc >= 4) __builtin_amdgcn_s_setprio(1);

  // WU fragments for (dir, all gates, tile tc): 32 frags
  s16x8 wu[4][8];   // [gate][kc]: kc 0-3 = W, 4-7 = U
#pragma unroll
  for (int g = 0; g < 4; g++)
#pragma unroll
    for (int kc = 0; kc < 8; kc++)
      wu[g][kc] = *(const s16x8*)(frag +
          ((((size_t)(dir * 4 + g) * 8 + kc) * 8 + tc) * 64 + lane) * 8);

  const float* bias = dir ? bbw : bfw;
  float bv[4];
#pragma unroll
  for (int g = 0; g < 4; g++) bv[g] = bias[g * 128 + tc * 16 + m];

  // x staging: thread -> xbuf row (tid>>5) = 4*br+ts, cols (tid&31)*4 (+3)
  int xrow = tid >> 5, xcol = (tid & 31) * 4;
  int sbr = xrow >> 2, sts = xrow & 3;
  const float* xsrc = x + ((size_t)(bblk * 4 + sbr) * NT) * 128 + xcol;

  auto tmap = [&](int s) { int ss = s > NT - 1 ? NT - 1 : s; return dir ? (NT - 1 - ss) : ss; };
  auto ldx4 = [&](int G) -> float4 {           // this thread's x word for group G
    return *(const float4*)(xsrc + (size_t)tmap(4 * G + sts) * 128);
  };
  auto stx = [&](int p, float4 v) {
    uint2 pk; pk.x = packbf2(v.x, v.y); pk.y = packbf2(v.z, v.w);
    *(uint2*)(&xbuf[p][xrow][xcol]) = pk;
  };

  // zero hbuf (padding rows must read 0 forever; h(0) = 0)
  {
    unsigned int* zp = (unsigned int*)&hbuf[0][0][0];
    for (int i = tid; i < 2 * 16 * 68; i += 512) zp[i] = 0;
  }
  // prologue staging: xbuf[0] = x(group 0), xbuf[1] = x(group 1)
  stx(0, ldx4(0));
  stx(1, ldx4(1));
  __syncthreads();

  // prologue: accX0 = b + x(group 0)@W  (dense, all rows real)
  s16x8 ax[4];
#pragma unroll
  for (int kk = 0; kk < 4; kk++)
    ax[kk] = *(const s16x8*)(&xbuf[0][m][kk * 32 + quad * 8]);
  f32x4 accX0[4], accX1[4];
#pragma unroll
  for (int g = 0; g < 4; g++) {
    accX0[g][0] = bv[g]; accX0[g][1] = bv[g]; accX0[g][2] = bv[g]; accX0[g][3] = bv[g];
  }
#pragma unroll
  for (int kk = 0; kk < 4; kk++)
#pragma unroll
    for (int g = 0; g < 4; g++)
      accX0[g] = __builtin_amdgcn_mfma_f32_16x16x32_bf16(ax[kk], wu[g][kk], accX0[g], 0, 0, 0);

  float4 vslot = ldx4(2);   // register prefetch slot (x for group 2)

  s16x8 ah[4];
#pragma unroll
  for (int kk = 0; kk < 4; kk++) ah[kk] = (s16x8){0, 0, 0, 0, 0, 0, 0, 0};

  // persistent serial-chain accumulator: only elem 0 is ever real; elems
  // 1..3 (padding C rows) receive zero contributions forever -> init once.
  f32x4 accS[4];
#pragma unroll
  for (int g = 0; g < 4; g++) {
    accS[g][0] = 0.f; accS[g][1] = 0.f; accS[g][2] = 0.f; accS[g][3] = 0.f;
  }

  float cc = 0.f;   // cell state: lane owns (batch row quad, col tc*16+m)
  float* outp = out + ((size_t)(bblk * 4 + quad) * NT) * 256 + dir * 128 + tc * 16 + m;

  // one recurrent sub-step; sub is a literal -> all indexing static
  auto substep = [&](int s, int sub, int p, f32x4 (&accXc)[4], f32x4 (&accXn)[4]) {
    int cb = s & 1, nb = cb ^ 1;

    // h(s) A-frags, exec-masked to real-row lanes (2-way banks, free)
    if (mrow) {
#pragma unroll
      for (int kk = 0; kk < 4; kk++)
        ah[kk] = *(const s16x8*)(&hbuf[cb][m][kk * 32 + quad * 8]);
    }
    if (sub == 0) {
      // dense x A-frags for group G+1 (off-chain)
#pragma unroll
      for (int kk = 0; kk < 4; kk++)
        ax[kk] = *(const s16x8*)(&xbuf[p ^ 1][m][kk * 32 + quad * 8]);
#pragma unroll
      for (int g = 0; g < 4; g++) {
        accXn[g][0] = bv[g]; accXn[g][1] = bv[g]; accXn[g][2] = bv[g]; accXn[g][3] = bv[g];
      }
    }

    // per-gate pipeline: gate chain, then its activation under later chains.
    accS[0][0] = accXc[0][sub];
#pragma unroll
    for (int kk = 0; kk < 4; kk++)
      accS[0] = __builtin_amdgcn_mfma_f32_16x16x32_bf16(ah[kk], wu[0][4 + kk], accS[0], 0, 0, 0);

    accS[1][0] = accXc[1][sub];
#pragma unroll
    for (int kk = 0; kk < 4; kk++)
      accS[1] = __builtin_amdgcn_mfma_f32_16x16x32_bf16(ah[kk], wu[1][4 + kk], accS[1], 0, 0, 0);
    float iv = sigm(accS[0][0]);

    accS[2][0] = accXc[2][sub];
#pragma unroll
    for (int kk = 0; kk < 4; kk++)
      accS[2] = __builtin_amdgcn_mfma_f32_16x16x32_bf16(ah[kk], wu[2][4 + kk], accS[2], 0, 0, 0);
    float fv = sigm(accS[1][0]);

    accS[3][0] = accXc[3][sub];
#pragma unroll
    for (int kk = 0; kk < 4; kk++)
      accS[3] = __builtin_amdgcn_mfma_f32_16x16x32_bf16(ah[kk], wu[3][4 + kk], accS[3], 0, 0, 0);
    float gv = tanh_(accS[2][0]);

    // off-chain: one dense kc for next group's accX
#pragma unroll
    for (int g = 0; g < 4; g++)
      accXn[g] = __builtin_amdgcn_mfma_f32_16x16x32_bf16(ax[sub], wu[g][sub], accXn[g], 0, 0, 0);

    float ov = sigm(accS[3][0]);
    cc = fv * cc + iv * gv;
    float hv = ov * tanh_(cc);

    hbuf[nb][quad * 4][tc * 16 + m] = f2bf(hv);   // gates the lgkm drain
    outp[(size_t)s * 256] = hv;                   // stays in flight past barrier

    // pin the interleave (best-effort; unclaimed instrs float):
    SGB(0x100, 4, 0);   // ah ds_reads
    SGB(0x8, 4, 0);     // g0 chain
    SGB(0x8, 4, 0);     // g1 chain
    SGB(0x2, 4, 0);     // iv
    SGB(0x8, 4, 0);     // g2 chain
    SGB(0x2, 4, 0);     // fv
    SGB(0x8, 4, 0);     // g3 chain
    SGB(0x2, 7, 0);     // gv (tanh)
    SGB(0x8, 4, 0);     // X chain
    SGB(0x2, 20, 0);    // ov, cc, hv, f2bf, misc
    SGB(0x200, 1, 0);   // hbuf write
  };

  auto group = [&](int G, int p, f32x4 (&accXc)[4], f32x4 (&accXn)[4]) {
    int s0 = 4 * G;
    float4 vnew = ldx4(G + 3);    // issue early: consumed at (G+1).sub3
    substep(s0 + 0, 0, p, accXc, accXn);
    LDS_BARRIER();
    substep(s0 + 1, 1, p, accXc, accXn);
    LDS_BARRIER();
    substep(s0 + 2, 2, p, accXc, accXn);
    LDS_BARRIER();
    substep(s0 + 3, 3, p, accXc, accXn);
    stx(p, vslot);                // stage x(group G+2) into xbuf[p]
    LDS_BARRIER();
    vslot = vnew;
  };

  for (int G = 0; G < NG; G += 2) {
    group(G, 0, accX0, accX1);
    group(G + 1, 1, accX1, accX0);
  }
}

extern "C" void kernel_launch(void* const* d_in, const int* in_sizes, int n_in,
                              void* d_out, int out_size, void* d_ws, size_t ws_size,
                              hipStream_t stream) {
  const float* x  = (const float*)d_in[0];
  const float* Wf = (const float*)d_in[1];
  const float* Uf = (const float*)d_in[2];
  const float* bf = (const float*)d_in[3];
  const float* Wb = (const float*)d_in[4];
  const float* Ub = (const float*)d_in[5];
  const float* bb = (const float*)d_in[6];
  float* out = (float*)d_out;

  unsigned short* frag = (unsigned short*)d_ws;

  prep_frags<<<1024, 256, 0, stream>>>(Wf, Uf, Wb, Ub, frag);
  bilstm_rec<<<128, 512, 0, stream>>>(frag, x, bf, bb, out);
}